// Round 14
// baseline (120.029 us; speedup 1.0000x reference)
//
#include <hip/hip_runtime.h>
#include <hip/hip_bf16.h>
#include <hip/hip_fp16.h>

#define EPS 1e-5f
#define CAP 64   // bucket capacity (Poisson(16) overflow ~1e-18/node)

typedef __attribute__((ext_vector_type(8))) short short8_t;            // 8 bf16 (MFMA operand)
typedef __attribute__((ext_vector_type(8))) unsigned short ushort8_t;  // 8 bf16 storage
typedef __attribute__((ext_vector_type(4))) float f32x4_t;             // MFMA accumulator

__device__ inline unsigned short f2bf(float f) {              // f32 -> bf16 RNE
    unsigned int u = __float_as_uint(f);
    unsigned int r = (u + 0x7FFFu + ((u >> 16) & 1u)) >> 16;
    return (unsigned short)r;
}
__device__ inline float bf2f(unsigned short h) {
    return __uint_as_float((unsigned int)h << 16);
}

// --------------------------------------- prep: zero + seg + convert + out ----
__global__ void prep_kernel(const float* __restrict__ x, unsigned short* __restrict__ xb,
                            int* __restrict__ cursor, float* __restrict__ st,
                            const int* __restrict__ batch, int* __restrict__ seg,
                            float* __restrict__ out, const float* __restrict__ bf2,
                            int n, int G) {
    int i = blockIdx.x * blockDim.x + threadIdx.x;
    if (i < n * 8) {               // one ushort8 (8 feats) per thread; x row = 64 feats
        const float4* xf4 = (const float4*)x;
        float4 u = xf4[i * 2];
        float4 v = xf4[i * 2 + 1];
        ushort8_t h;
        h[0] = f2bf(u.x); h[1] = f2bf(u.y); h[2] = f2bf(u.z); h[3] = f2bf(u.w);
        h[4] = f2bf(v.x); h[5] = f2bf(v.y); h[6] = f2bf(v.z); h[7] = f2bf(v.w);
        ((ushort8_t*)xb)[i] = h;
    }
    if (i < n) cursor[i] = 0;
    if (i < 1028) st[i] = 0.f;     // st1[256] | st2[512] | stf[256] | ctr
    if (i < G) out[i] = bf2[0];
    if (i <= G) {
        if (i == G) { seg[G] = n; }
        else {
            int lo = 0, hi = n;
            while (lo < hi) {
                int mid = (lo + hi) >> 1;
                if (batch[mid] < i) lo = mid + 1; else hi = mid;
            }
            seg[i] = lo;
        }
    }
}

// ----------------------------------------------------------- bucket fill ----
__global__ void fillb_kernel(const int* __restrict__ ei, int* __restrict__ cursor,
                             unsigned short* __restrict__ recs, int E) {
    int e = blockIdx.x * blockDim.x + threadIdx.x;
    if (e >= E) return;
    int r = ei[e];
    int c = ei[E + e];
    int pos = atomicAdd(&cursor[c], 1);
    recs[(size_t)c * CAP + pos] = (unsigned short)r;
}

// --------------------------------------------------------- MFMA GEMM body ----
// (used by the solv FC tiles) OMODE: 0 f32, 1 bf16, 2 relu bf16. A_F32: convert.
template <int K, int NTOT, int OMODE, bool A_F32, bool STATS>
__device__ void gemm_body(char* smemc, int row0, int col0,
                          const void* __restrict__ A, int lda,
                          const float* __restrict__ B, const float* __restrict__ bias,
                          void* __restrict__ Cout, int ldc, float* __restrict__ st, int M) {
    constexpr int KP = K + 8;
    unsigned short (*As)[KP] = (unsigned short (*)[KP])smemc;
    unsigned short (*Bs)[KP] = (unsigned short (*)[KP])(smemc + (size_t)64 * KP * 2);
    float (*sred)[64][2]     = (float (*)[64][2])(smemc + (size_t)2 * 64 * KP * 2);

    const int t    = threadIdx.x;
    const int lane = t & 63;
    const int wave = t >> 6;
    const int wr   = wave >> 1;
    const int wc   = wave & 1;

    constexpr int PA = (64 * K / 8) / 256;
#pragma unroll
    for (int p = 0; p < PA; p++) {
        int fi = t + 256 * p;
        int r  = fi / (K / 8);
        int c8 = fi % (K / 8);
        ushort8_t v = {};
        if (row0 + r < M) {
            if (A_F32) {
                const float* Af = (const float*)A;
                float4 u0 = *(const float4*)&Af[(size_t)(row0 + r) * lda + c8 * 8];
                float4 u1 = *(const float4*)&Af[(size_t)(row0 + r) * lda + c8 * 8 + 4];
                v[0] = f2bf(u0.x); v[1] = f2bf(u0.y); v[2] = f2bf(u0.z); v[3] = f2bf(u0.w);
                v[4] = f2bf(u1.x); v[5] = f2bf(u1.y); v[6] = f2bf(u1.z); v[7] = f2bf(u1.w);
            } else {
                v = *(const ushort8_t*)&((const unsigned short*)A)[(size_t)(row0 + r) * lda + c8 * 8];
            }
        }
        *(ushort8_t*)&As[r][c8 * 8] = v;
    }
    constexpr int PB = (K * 16) / 256;
#pragma unroll
    for (int p = 0; p < PB; p++) {
        int fi = t + 256 * p;
        int k  = fi >> 4;
        int c4 = fi & 15;
        float4 v = *(const float4*)&B[(size_t)k * NTOT + col0 + c4 * 4];
        Bs[c4 * 4 + 0][k] = f2bf(v.x);
        Bs[c4 * 4 + 1][k] = f2bf(v.y);
        Bs[c4 * 4 + 2][k] = f2bf(v.z);
        Bs[c4 * 4 + 3][k] = f2bf(v.w);
    }
    __syncthreads();

    const int l15 = lane & 15;
    const int l16 = lane >> 4;
    f32x4_t acc[2][2] = {};
#pragma unroll
    for (int ks = 0; ks < K / 32; ks++) {
        int koff = ks * 32 + l16 * 8;
        short8_t a0 = *(const short8_t*)&As[wr * 32 + l15][koff];
        short8_t a1 = *(const short8_t*)&As[wr * 32 + 16 + l15][koff];
        short8_t b0 = *(const short8_t*)&Bs[wc * 32 + l15][koff];
        short8_t b1 = *(const short8_t*)&Bs[wc * 32 + 16 + l15][koff];
        acc[0][0] = __builtin_amdgcn_mfma_f32_16x16x32_bf16(a0, b0, acc[0][0], 0, 0, 0);
        acc[0][1] = __builtin_amdgcn_mfma_f32_16x16x32_bf16(a0, b1, acc[0][1], 0, 0, 0);
        acc[1][0] = __builtin_amdgcn_mfma_f32_16x16x32_bf16(a1, b0, acc[1][0], 0, 0, 0);
        acc[1][1] = __builtin_amdgcn_mfma_f32_16x16x32_bf16(a1, b1, acc[1][1], 0, 0, 0);
    }

    float s1[2] = {0.f, 0.f}, s2[2] = {0.f, 0.f};
#pragma unroll
    for (int m = 0; m < 2; m++) {
#pragma unroll
        for (int j = 0; j < 4; j++) {
            int row = row0 + wr * 32 + m * 16 + l16 * 4 + j;
            if (row < M) {
#pragma unroll
                for (int nn = 0; nn < 2; nn++) {
                    int col = col0 + wc * 32 + nn * 16 + l15;
                    float v = acc[m][nn][j] + bias[col];
                    if (OMODE == 2) v = fmaxf(v, 0.f);
                    if (OMODE == 0) ((float*)Cout)[(size_t)row * ldc + col] = v;
                    else ((unsigned short*)Cout)[(size_t)row * ldc + col] = f2bf(v);
                    if (STATS) { s1[nn] += v; s2[nn] += v * v; }
                }
            }
        }
    }
    if (STATS) {
#pragma unroll
        for (int nn = 0; nn < 2; nn++) {
            s1[nn] += __shfl_xor(s1[nn], 16);
            s1[nn] += __shfl_xor(s1[nn], 32);
            s2[nn] += __shfl_xor(s2[nn], 16);
            s2[nn] += __shfl_xor(s2[nn], 32);
        }
        if (lane < 16) {
#pragma unroll
            for (int nn = 0; nn < 2; nn++) {
                sred[wr][wc * 32 + nn * 16 + lane][0] = s1[nn];
                sred[wr][wc * 32 + nn * 16 + lane][1] = s2[nn];
            }
        }
        __syncthreads();
        if (t < 64) {
            float a = sred[0][t][0] + sred[1][t][0];
            float b = sred[0][t][1] + sred[1][t][1];
            atomicAdd(&st[col0 + t], a);
            atomicAdd(&st[NTOT + col0 + t], b);
        }
    }
}

// --------------------------------------- gemm1f: gather1 + gemm1 (+ solv) ----
// blocks [0,MT): A-rows gathered in-LDS from xb (inline f32 weights); tile 64x128.
// blocks [MT, MT+16): solv FC tiles (relu(sf@Ws+bs) -> zs bf16).
__global__ __launch_bounds__(256)
void gemm1f_kernel(const unsigned short* __restrict__ xb, const int* __restrict__ cursor,
                   const unsigned short* __restrict__ recs,
                   const float* __restrict__ W1, const float* __restrict__ b1,
                   unsigned short* __restrict__ h1b, float* __restrict__ st1,
                   const float* __restrict__ sf, const float* __restrict__ Ws,
                   const float* __restrict__ bs, unsigned short* __restrict__ zs,
                   int n, int MT, int G) {
    __shared__ alignas(16) char smem[35840];
    const int bid = blockIdx.x;
    const int t   = threadIdx.x;

    if (bid >= MT) {   // solv FC
        int s = bid - MT;
        gemm_body<128, 128, 2, true, false>(smem, (s >> 1) * 64, (s & 1) * 64,
                                            sf, 128, Ws, bs, zs, 128, nullptr, G);
        return;
    }

    constexpr int KP = 72;   // 64 + 8 pad (144B rows, 16B-aligned)
    unsigned short (*As)[KP] = (unsigned short (*)[KP])smem;              // 9216 B
    unsigned short (*Bs)[KP] = (unsigned short (*)[KP])(smem + 9216);     // 128x72x2 = 18432
    float (*sred)[64][2]     = (float (*)[64][2])(smem + 9216 + 18432);   // 1024
    const int row0 = bid * 64;

    // gather phase: 2 passes x 32 nodes; 8 lanes/node, 1 ushort8 (8 feats)/lane
    for (int pp = 0; pp < 2; pp++) {
        int node  = row0 + pp * 32 + (t >> 3);
        int lane8 = t & 7;
        float acc[8] = {}, acc2[8] = {};
        bool valid = node < n;
        float di = 0.f;
        if (valid) {
            const ushort8_t* src8 = (const ushort8_t*)xb;
            int deg = cursor[node];
            di = rsqrtf((float)deg + 1.f);
            ushort8_t sv = src8[(size_t)node * 8 + lane8];
#pragma unroll
            for (int j = 0; j < 8; j++) acc[j] = bf2f(sv[j]) * di;
            int e = node * CAP, e1 = e + deg;
            for (; e + 1 < e1; e += 2) {
                int r0 = recs[e], r1 = recs[e + 1];
                float w0 = rsqrtf((float)cursor[r0] + 1.f);
                float w1 = rsqrtf((float)cursor[r1] + 1.f);
                ushort8_t v0 = src8[(size_t)r0 * 8 + lane8];
                ushort8_t v1 = src8[(size_t)r1 * 8 + lane8];
#pragma unroll
                for (int j = 0; j < 8; j++) {
                    acc[j]  = fmaf(bf2f(v0[j]), w0, acc[j]);
                    acc2[j] = fmaf(bf2f(v1[j]), w1, acc2[j]);
                }
            }
            if (e < e1) {
                int r0 = recs[e];
                float w0 = rsqrtf((float)cursor[r0] + 1.f);
                ushort8_t v0 = src8[(size_t)r0 * 8 + lane8];
#pragma unroll
                for (int j = 0; j < 8; j++) acc[j] = fmaf(bf2f(v0[j]), w0, acc[j]);
            }
        }
        ushort8_t o = {};
        if (valid) {
#pragma unroll
            for (int j = 0; j < 8; j++) o[j] = f2bf((acc[j] + acc2[j]) * di);
        }
        *(ushort8_t*)&As[pp * 32 + (t >> 3)][lane8 * 8] = o;
    }

    // stage Bs: W1 [64][128] f32 -> Bs[col][k]
#pragma unroll
    for (int p = 0; p < 8; p++) {
        int fi = t + 256 * p;      // 2048 float4 items
        int k  = fi >> 5;          // 32 float4s per k-row
        int c4 = fi & 31;
        float4 v = *(const float4*)&W1[(size_t)k * 128 + c4 * 4];
        Bs[c4 * 4 + 0][k] = f2bf(v.x);
        Bs[c4 * 4 + 1][k] = f2bf(v.y);
        Bs[c4 * 4 + 2][k] = f2bf(v.z);
        Bs[c4 * 4 + 3][k] = f2bf(v.w);
    }
    __syncthreads();

    const int lane = t & 63, wave = t >> 6, wr = wave >> 1, wc = wave & 1;
    const int l15 = lane & 15, l16 = lane >> 4;
    f32x4_t acc[2][2][2] = {};   // [colpass][m][nn]
#pragma unroll
    for (int ks = 0; ks < 2; ks++) {
        int koff = ks * 32 + l16 * 8;
        short8_t a0 = *(const short8_t*)&As[wr * 32 + l15][koff];
        short8_t a1 = *(const short8_t*)&As[wr * 32 + 16 + l15][koff];
#pragma unroll
        for (int p2 = 0; p2 < 2; p2++) {
            short8_t b0 = *(const short8_t*)&Bs[p2 * 64 + wc * 32 + l15][koff];
            short8_t b1 = *(const short8_t*)&Bs[p2 * 64 + wc * 32 + 16 + l15][koff];
            acc[p2][0][0] = __builtin_amdgcn_mfma_f32_16x16x32_bf16(a0, b0, acc[p2][0][0], 0, 0, 0);
            acc[p2][0][1] = __builtin_amdgcn_mfma_f32_16x16x32_bf16(a0, b1, acc[p2][0][1], 0, 0, 0);
            acc[p2][1][0] = __builtin_amdgcn_mfma_f32_16x16x32_bf16(a1, b0, acc[p2][1][0], 0, 0, 0);
            acc[p2][1][1] = __builtin_amdgcn_mfma_f32_16x16x32_bf16(a1, b1, acc[p2][1][1], 0, 0, 0);
        }
    }

    for (int p2 = 0; p2 < 2; p2++) {
        if (p2) __syncthreads();
        float s1[2] = {0.f, 0.f}, s2[2] = {0.f, 0.f};
#pragma unroll
        for (int m = 0; m < 2; m++)
#pragma unroll
            for (int j = 0; j < 4; j++) {
                int row = row0 + wr * 32 + m * 16 + l16 * 4 + j;
                if (row < n) {
#pragma unroll
                    for (int nn = 0; nn < 2; nn++) {
                        int col = p2 * 64 + wc * 32 + nn * 16 + l15;
                        float v = acc[p2][m][nn][j] + b1[col];
                        h1b[(size_t)row * 128 + col] = f2bf(v);
                        s1[nn] += v;
                        s2[nn] += v * v;
                    }
                }
            }
#pragma unroll
        for (int nn = 0; nn < 2; nn++) {
            s1[nn] += __shfl_xor(s1[nn], 16);
            s1[nn] += __shfl_xor(s1[nn], 32);
            s2[nn] += __shfl_xor(s2[nn], 16);
            s2[nn] += __shfl_xor(s2[nn], 32);
        }
        if (lane < 16) {
#pragma unroll
            for (int nn = 0; nn < 2; nn++) {
                sred[wr][wc * 32 + nn * 16 + lane][0] = s1[nn];
                sred[wr][wc * 32 + nn * 16 + lane][1] = s2[nn];
            }
        }
        __syncthreads();
        if (t < 64) {
            atomicAdd(&st1[p2 * 64 + t],       sred[0][t][0] + sred[1][t][0]);
            atomicAdd(&st1[128 + p2 * 64 + t], sred[0][t][1] + sred[1][t][1]);
        }
    }
}

// --------------------------------------------- gemm2f: gather2 + gemm2 ----
// tile 64 rows x 256 cols; A-rows = relu(BN1(a1)) gathered in-LDS.
__global__ __launch_bounds__(256)
void gemm2f_kernel(const unsigned short* __restrict__ a1, const int* __restrict__ cursor,
                   const unsigned short* __restrict__ recs,
                   const float* __restrict__ st1, const float* __restrict__ g1,
                   const float* __restrict__ be1, float inv_n,
                   const float* __restrict__ W2, const float* __restrict__ b2,
                   unsigned short* __restrict__ a2b, float* __restrict__ st2, int n) {
    constexpr int KP = 136;
    __shared__ unsigned short As[64][KP];     // 17408
    __shared__ unsigned short Bs[64][KP];     // 17408
    __shared__ float scs[128], shs[128];
    __shared__ float sred[2][64][2];
    const int t    = threadIdx.x;
    const int row0 = blockIdx.x * 64;

    if (t < 128) {
        float m   = st1[t] * inv_n;
        float var = st1[128 + t] * inv_n - m * m;
        float sc  = g1[t] * rsqrtf(var + EPS);
        scs[t] = sc;
        shs[t] = be1[t] - m * sc;
    }
    __syncthreads();

    // gather phase: 2 passes x 32 nodes; 8 lanes/node, 2 ushort8s (16 feats)/lane
    for (int pp = 0; pp < 2; pp++) {
        int node  = row0 + pp * 32 + (t >> 3);
        int lane8 = t & 7;
        int f0    = lane8 * 16;
        float sc[16], sh[16];
#pragma unroll
        for (int j = 0; j < 16; j++) { sc[j] = scs[f0 + j]; sh[j] = shs[f0 + j]; }
        float acc[16] = {}, acc2[16] = {};
        bool valid = node < n;
        float di = 0.f;
        if (valid) {
            const ushort8_t* src8 = (const ushort8_t*)a1;
            int deg = cursor[node];
            di = rsqrtf((float)deg + 1.f);
            ushort8_t sv0 = src8[(size_t)node * 16 + lane8 * 2];
            ushort8_t sv1 = src8[(size_t)node * 16 + lane8 * 2 + 1];
#pragma unroll
            for (int j = 0; j < 8; j++) {
                acc[j]     = fmaxf(fmaf(bf2f(sv0[j]), sc[j],     sh[j]),     0.f) * di;
                acc[8 + j] = fmaxf(fmaf(bf2f(sv1[j]), sc[8 + j], sh[8 + j]), 0.f) * di;
            }
            int e = node * CAP, e1 = e + deg;
            for (; e + 1 < e1; e += 2) {
                int r0 = recs[e], r1 = recs[e + 1];
                float w0 = rsqrtf((float)cursor[r0] + 1.f);
                float w1 = rsqrtf((float)cursor[r1] + 1.f);
                ushort8_t u0 = src8[(size_t)r0 * 16 + lane8 * 2];
                ushort8_t u1 = src8[(size_t)r0 * 16 + lane8 * 2 + 1];
                ushort8_t u2 = src8[(size_t)r1 * 16 + lane8 * 2];
                ushort8_t u3 = src8[(size_t)r1 * 16 + lane8 * 2 + 1];
#pragma unroll
                for (int j = 0; j < 8; j++) {
                    acc[j]      = fmaf(fmaxf(fmaf(bf2f(u0[j]), sc[j],     sh[j]),     0.f), w0, acc[j]);
                    acc[8 + j]  = fmaf(fmaxf(fmaf(bf2f(u1[j]), sc[8 + j], sh[8 + j]), 0.f), w0, acc[8 + j]);
                    acc2[j]     = fmaf(fmaxf(fmaf(bf2f(u2[j]), sc[j],     sh[j]),     0.f), w1, acc2[j]);
                    acc2[8 + j] = fmaf(fmaxf(fmaf(bf2f(u3[j]), sc[8 + j], sh[8 + j]), 0.f), w1, acc2[8 + j]);
                }
            }
            if (e < e1) {
                int r0 = recs[e];
                float w0 = rsqrtf((float)cursor[r0] + 1.f);
                ushort8_t u0 = src8[(size_t)r0 * 16 + lane8 * 2];
                ushort8_t u1 = src8[(size_t)r0 * 16 + lane8 * 2 + 1];
#pragma unroll
                for (int j = 0; j < 8; j++) {
                    acc[j]     = fmaf(fmaxf(fmaf(bf2f(u0[j]), sc[j],     sh[j]),     0.f), w0, acc[j]);
                    acc[8 + j] = fmaf(fmaxf(fmaf(bf2f(u1[j]), sc[8 + j], sh[8 + j]), 0.f), w0, acc[8 + j]);
                }
            }
        }
        ushort8_t o0 = {}, o1 = {};
        if (valid) {
#pragma unroll
            for (int j = 0; j < 8; j++) {
                o0[j] = f2bf((acc[j] + acc2[j]) * di);
                o1[j] = f2bf((acc[8 + j] + acc2[8 + j]) * di);
            }
        }
        *(ushort8_t*)&As[pp * 32 + (t >> 3)][lane8 * 16]     = o0;
        *(ushort8_t*)&As[pp * 32 + (t >> 3)][lane8 * 16 + 8] = o1;
    }

    const int lane = t & 63, wave = t >> 6, wr = wave >> 1, wc = wave & 1;
    const int l15 = lane & 15, l16 = lane >> 4;

    for (int cc = 0; cc < 4; cc++) {
        __syncthreads();   // As ready / Bs+sred reuse safe
#pragma unroll
        for (int p = 0; p < 8; p++) {     // Bs <- W2[:, cc*64..] transposed
            int fi = t + 256 * p;         // 2048 float4 items
            int k  = fi >> 4;             // 16 float4s per k-row chunk
            int c4 = fi & 15;
            float4 v = *(const float4*)&W2[(size_t)k * 256 + cc * 64 + c4 * 4];
            Bs[c4 * 4 + 0][k] = f2bf(v.x);
            Bs[c4 * 4 + 1][k] = f2bf(v.y);
            Bs[c4 * 4 + 2][k] = f2bf(v.z);
            Bs[c4 * 4 + 3][k] = f2bf(v.w);
        }
        __syncthreads();
        f32x4_t acc[2][2] = {};
#pragma unroll
        for (int ks = 0; ks < 4; ks++) {
            int koff = ks * 32 + l16 * 8;
            short8_t a0 = *(const short8_t*)&As[wr * 32 + l15][koff];
            short8_t a1 = *(const short8_t*)&As[wr * 32 + 16 + l15][koff];
            short8_t b0 = *(const short8_t*)&Bs[wc * 32 + l15][koff];
            short8_t b1 = *(const short8_t*)&Bs[wc * 32 + 16 + l15][koff];
            acc[0][0] = __builtin_amdgcn_mfma_f32_16x16x32_bf16(a0, b0, acc[0][0], 0, 0, 0);
            acc[0][1] = __builtin_amdgcn_mfma_f32_16x16x32_bf16(a0, b1, acc[0][1], 0, 0, 0);
            acc[1][0] = __builtin_amdgcn_mfma_f32_16x16x32_bf16(a1, b0, acc[1][0], 0, 0, 0);
            acc[1][1] = __builtin_amdgcn_mfma_f32_16x16x32_bf16(a1, b1, acc[1][1], 0, 0, 0);
        }
        float s1[2] = {0.f, 0.f}, s2[2] = {0.f, 0.f};
#pragma unroll
        for (int m = 0; m < 2; m++)
#pragma unroll
            for (int j = 0; j < 4; j++) {
                int row = row0 + wr * 32 + m * 16 + l16 * 4 + j;
                if (row < n) {
#pragma unroll
                    for (int nn = 0; nn < 2; nn++) {
                        int col = cc * 64 + wc * 32 + nn * 16 + l15;
                        float v = acc[m][nn][j] + b2[col];
                        a2b[(size_t)row * 256 + col] = f2bf(v);
                        s1[nn] += v;
                        s2[nn] += v * v;
                    }
                }
            }
#pragma unroll
        for (int nn = 0; nn < 2; nn++) {
            s1[nn] += __shfl_xor(s1[nn], 16);
            s1[nn] += __shfl_xor(s1[nn], 32);
            s2[nn] += __shfl_xor(s2[nn], 16);
            s2[nn] += __shfl_xor(s2[nn], 32);
        }
        if (lane < 16) {
#pragma unroll
            for (int nn = 0; nn < 2; nn++) {
                sred[wr][wc * 32 + nn * 16 + lane][0] = s1[nn];
                sred[wr][wc * 32 + nn * 16 + lane][1] = s2[nn];
            }
        }
        __syncthreads();
        if (t < 64) {
            atomicAdd(&st2[cc * 64 + t],       sred[0][t][0] + sred[1][t][0]);
            atomicAdd(&st2[256 + cc * 64 + t], sred[0][t][1] + sred[1][t][1]);
        }
    }
}

// ------------------------------------------------------------------ pool ----
// block g: z[g][0..256) = bf16( mean_i relu(BN2(a2)) ); a2 is bf16 now.
__launch_bounds__(256)
__global__ void pool_kernel(const unsigned short* __restrict__ a2b, const int* __restrict__ seg,
                            const float* __restrict__ st2, const float* __restrict__ g2,
                            const float* __restrict__ be2, float inv_n,
                            unsigned short* __restrict__ z) {
    __shared__ float4 red[4][64];
    int g  = blockIdx.x;
    int t  = threadIdx.x;
    int r  = t >> 6;
    int f4 = t & 63;

    float4 sc, sh;
    {
        float m0 = st2[f4 * 4 + 0] * inv_n, m1 = st2[f4 * 4 + 1] * inv_n;
        float m2 = st2[f4 * 4 + 2] * inv_n, m3 = st2[f4 * 4 + 3] * inv_n;
        sc.x = g2[f4 * 4 + 0] * rsqrtf(st2[256 + f4 * 4 + 0] * inv_n - m0 * m0 + EPS);
        sc.y = g2[f4 * 4 + 1] * rsqrtf(st2[256 + f4 * 4 + 1] * inv_n - m1 * m1 + EPS);
        sc.z = g2[f4 * 4 + 2] * rsqrtf(st2[256 + f4 * 4 + 2] * inv_n - m2 * m2 + EPS);
        sc.w = g2[f4 * 4 + 3] * rsqrtf(st2[256 + f4 * 4 + 3] * inv_n - m3 * m3 + EPS);
        sh.x = be2[f4 * 4 + 0] - m0 * sc.x;
        sh.y = be2[f4 * 4 + 1] - m1 * sc.y;
        sh.z = be2[f4 * 4 + 2] - m2 * sc.z;
        sh.w = be2[f4 * 4 + 3] - m3 * sc.w;
    }

    int i0 = seg[g], i1 = seg[g + 1];
    float4 acc = make_float4(0.f, 0.f, 0.f, 0.f);
    for (int i = i0 + r; i < i1; i += 4) {
        ushort4 v = *(const ushort4*)&a2b[(size_t)i * 256 + f4 * 4];
        acc.x += fmaxf(fmaf(bf2f(v.x), sc.x, sh.x), 0.f);
        acc.y += fmaxf(fmaf(bf2f(v.y), sc.y, sh.y), 0.f);
        acc.z += fmaxf(fmaf(bf2f(v.z), sc.z, sh.z), 0.f);
        acc.w += fmaxf(fmaf(bf2f(v.w), sc.w, sh.w), 0.f);
    }
    red[r][f4] = acc;
    __syncthreads();
    if (t < 64) {
        float4 a = red[0][t], b = red[1][t], c = red[2][t], d = red[3][t];
        float inv = 1.0f / fmaxf((float)(i1 - i0), 1.f);
        ushort4 o;
        o.x = f2bf((a.x + b.x + c.x + d.x) * inv);
        o.y = f2bf((a.y + b.y + c.y + d.y) * inv);
        o.z = f2bf((a.z + b.z + c.z + d.z) * inv);
        o.w = f2bf((a.w + b.w + c.w + d.w) * inv);
        *(ushort4*)&z[(size_t)g * 256 + t * 4] = o;
    }
}

// ------------------------------------------------------------------ head ----
__global__ __launch_bounds__(256)
void head_kernel(const unsigned short* __restrict__ z, const unsigned short* __restrict__ zs,
                 const float* __restrict__ Wf1, const float* __restrict__ bf1,
                 const float* __restrict__ gf, const float* __restrict__ bef,
                 const float* __restrict__ Wf2,
                 float* __restrict__ stf, int* __restrict__ ctr,
                 float* __restrict__ out, float inv_g, int nblocks) {
    constexpr int KP = 136;
    __shared__ unsigned short As[64][KP];
    __shared__ unsigned short Bs[64][KP];
    __shared__ float sred[2][64][2];

    const int t    = threadIdx.x;
    const int lane = t & 63;
    const int wave = t >> 6;
    const int wr   = wave >> 1;
    const int wc   = wave & 1;
    const int row0 = (blockIdx.x >> 1) * 64;
    const int col0 = (blockIdx.x & 1) * 64;
    const int l15  = lane & 15;
    const int l16  = lane >> 4;

    f32x4_t acc[2][2] = {};
    for (int kc = 0; kc < 3; kc++) {
        __syncthreads();
#pragma unroll
        for (int p = 0; p < 4; p++) {
            int fi = t + 256 * p;
            int r  = fi >> 4, c8 = fi & 15;
            const unsigned short* ap = (kc < 2)
                ? &z[(size_t)(row0 + r) * 256 + kc * 128 + c8 * 8]
                : &zs[(size_t)(row0 + r) * 128 + c8 * 8];
            *(ushort8_t*)&As[r][c8 * 8] = *(const ushort8_t*)ap;
        }
#pragma unroll
        for (int p = 0; p < 8; p++) {
            int fi = t + 256 * p;
            int k  = fi >> 4, c4 = fi & 15;
            float4 v = *(const float4*)&Wf1[(size_t)(kc * 128 + k) * 128 + col0 + c4 * 4];
            Bs[c4 * 4 + 0][k] = f2bf(v.x);
            Bs[c4 * 4 + 1][k] = f2bf(v.y);
            Bs[c4 * 4 + 2][k] = f2bf(v.z);
            Bs[c4 * 4 + 3][k] = f2bf(v.w);
        }
        __syncthreads();
#pragma unroll
        for (int ks = 0; ks < 4; ks++) {
            int koff = ks * 32 + l16 * 8;
            short8_t a0 = *(const short8_t*)&As[wr * 32 + l15][koff];
            short8_t a1 = *(const short8_t*)&As[wr * 32 + 16 + l15][koff];
            short8_t b0 = *(const short8_t*)&Bs[wc * 32 + l15][koff];
            short8_t b1 = *(const short8_t*)&Bs[wc * 32 + 16 + l15][koff];
            acc[0][0] = __builtin_amdgcn_mfma_f32_16x16x32_bf16(a0, b0, acc[0][0], 0, 0, 0);
            acc[0][1] = __builtin_amdgcn_mfma_f32_16x16x32_bf16(a0, b1, acc[0][1], 0, 0, 0);
            acc[1][0] = __builtin_amdgcn_mfma_f32_16x16x32_bf16(a1, b0, acc[1][0], 0, 0, 0);
            acc[1][1] = __builtin_amdgcn_mfma_f32_16x16x32_bf16(a1, b1, acc[1][1], 0, 0, 0);
        }
    }

    float s1[2] = {0.f, 0.f}, s2[2] = {0.f, 0.f};
#pragma unroll
    for (int m = 0; m < 2; m++)
#pragma unroll
        for (int j = 0; j < 4; j++)
#pragma unroll
            for (int nn = 0; nn < 2; nn++) {
                int col = col0 + wc * 32 + nn * 16 + l15;
                float v = acc[m][nn][j] + bf1[col];
                acc[m][nn][j] = v;
                s1[nn] += v;
                s2[nn] += v * v;
            }
#pragma unroll
    for (int nn = 0; nn < 2; nn++) {
        s1[nn] += __shfl_xor(s1[nn], 16);
        s1[nn] += __shfl_xor(s1[nn], 32);
        s2[nn] += __shfl_xor(s2[nn], 16);
        s2[nn] += __shfl_xor(s2[nn], 32);
    }
    if (lane < 16) {
#pragma unroll
        for (int nn = 0; nn < 2; nn++) {
            sred[wr][wc * 32 + nn * 16 + lane][0] = s1[nn];
            sred[wr][wc * 32 + nn * 16 + lane][1] = s2[nn];
        }
    }
    __syncthreads();
    if (t < 64) {
        atomicAdd(&stf[col0 + t],       sred[0][t][0] + sred[1][t][0]);
        atomicAdd(&stf[128 + col0 + t], sred[0][t][1] + sred[1][t][1]);
    }

    __threadfence();
    __syncthreads();
    if (t == 0) {
        atomicAdd(ctr, 1);
        while (atomicAdd(ctr, 0) < nblocks) { }
    }
    __syncthreads();

    float* sflat = &sred[0][0][0];
    sflat[t] = atomicAdd(&stf[t], 0.f);
    __syncthreads();

#pragma unroll
    for (int m = 0; m < 2; m++)
#pragma unroll
        for (int j = 0; j < 4; j++) {
            float p = 0.f;
#pragma unroll
            for (int nn = 0; nn < 2; nn++) {
                int col = col0 + wc * 32 + nn * 16 + l15;
                float mean = sflat[col] * inv_g;
                float var  = sflat[128 + col] * inv_g - mean * mean;
                float sc   = gf[col] * rsqrtf(var + EPS);
                float sh   = bef[col] - mean * sc;
                p += fmaxf(fmaf(acc[m][nn][j], sc, sh), 0.f) * Wf2[col];
            }
            p += __shfl_xor(p, 1);
            p += __shfl_xor(p, 2);
            p += __shfl_xor(p, 4);
            p += __shfl_xor(p, 8);
            if (l15 == 0) {
                int row = wr * 32 + m * 16 + l16 * 4 + j;
                atomicAdd(&out[row0 + row], p);
            }
        }
}

// ---------------------------------------------------------------- launch ----
extern "C" void kernel_launch(void* const* d_in, const int* in_sizes, int n_in,
                              void* d_out, int out_size, void* d_ws, size_t ws_size,
                              hipStream_t stream) {
    const float* x    = (const float*)d_in[0];
    const int*   ei   = (const int*)d_in[1];
    const int*   batch= (const int*)d_in[2];
    const float* sf   = (const float*)d_in[3];
    const float* W1   = (const float*)d_in[4];
    const float* b1   = (const float*)d_in[5];
    const float* g1   = (const float*)d_in[6];
    const float* be1  = (const float*)d_in[7];
    const float* W2   = (const float*)d_in[8];
    const float* b2   = (const float*)d_in[9];
    const float* g2   = (const float*)d_in[10];
    const float* be2  = (const float*)d_in[11];
    const float* Ws   = (const float*)d_in[12];
    const float* bs   = (const float*)d_in[13];
    const float* Wf1  = (const float*)d_in[14];
    const float* bf1  = (const float*)d_in[15];
    const float* gf1  = (const float*)d_in[16];
    const float* bef1 = (const float*)d_in[17];
    const float* Wf2  = (const float*)d_in[18];
    const float* bf2  = (const float*)d_in[19];
    float* out = (float*)d_out;

    const int n = in_sizes[0] / 64;    // 20000 nodes
    const int E = in_sizes[1] / 2;     // 320000 edges
    const int G = in_sizes[3] / 128;   // 512 graphs

    // workspace (f32 units unless noted):
    // a2b[n*256 bf16 = 128n] | xb[32n] | h1b[64n] | z[G*128] | zs[G*64] |
    // st[1028] | cursor[n] | seg[G+1] | recs[n*CAP u16 = 32n]
    float* ws = (float*)d_ws;
    unsigned short* a2b = (unsigned short*)ws;
    unsigned short* xb  = (unsigned short*)(ws + (size_t)n * 128);
    unsigned short* h1b = (unsigned short*)(ws + (size_t)n * 160);
    unsigned short* z   = (unsigned short*)(ws + (size_t)n * 224);
    unsigned short* zs  = (unsigned short*)(ws + (size_t)n * 224 + (size_t)G * 128);
    float* st   = ws + (size_t)n * 224 + (size_t)G * 192;
    float* st1  = st;
    float* st2  = st + 256;
    float* stf  = st + 768;
    int*   ctr  = (int*)(st + 1024);
    int*   cursor = (int*)(st + 1028);
    int*   seg    = cursor + n;
    unsigned short* recs = (unsigned short*)(seg + G + 1);

    const float inv_nn = 1.0f / (float)n;
    const float inv_gg = 1.0f / (float)G;
    const int MT = (n + 63) / 64;

    prep_kernel<<<(n * 8 + 255) / 256, 256, 0, stream>>>(x, xb, cursor, st, batch, seg,
                                                         out, bf2, n, G);
    fillb_kernel<<<(E + 255) / 256, 256, 0, stream>>>(ei, cursor, recs, E);

    // gemm1f: [gather1 in-LDS] @ W1 -> a1 bf16 + st1 ; + solv FC tiles -> zs
    gemm1f_kernel<<<MT + (G / 64) * 2, 256, 0, stream>>>(
        xb, cursor, recs, W1, b1, h1b, st1, sf, Ws, bs, zs, n, MT, G);

    // gemm2f: [gather2(BN1) in-LDS] @ W2 -> a2 bf16 + st2
    gemm2f_kernel<<<MT, 256, 0, stream>>>(
        h1b, cursor, recs, st1, g1, be1, inv_nn, W2, b2, a2b, st2, n);

    // pool -> z (bf16 [G][256])
    pool_kernel<<<G, 256, 0, stream>>>(a2b, seg, st2, g2, be2, inv_nn, z);

    // head: fc1 + stats + barrier + final
    head_kernel<<<(G / 64) * 2, 256, 0, stream>>>(z, zs, Wf1, bf1, gf1, bef1, Wf2,
                                                  stf, ctr, out, inv_gg, (G / 64) * 2);
}

// Round 15
// 114.824 us; speedup vs baseline: 1.0453x; 1.0453x over previous
//
#include <hip/hip_runtime.h>
#include <hip/hip_bf16.h>
#include <hip/hip_fp16.h>

#define EPS 1e-5f
#define CAP 64   // bucket capacity (Poisson(16) overflow ~1e-18/node)

typedef __attribute__((ext_vector_type(8))) short short8_t;            // 8 bf16 (MFMA operand)
typedef __attribute__((ext_vector_type(8))) unsigned short ushort8_t;  // 8 bf16 storage
typedef __attribute__((ext_vector_type(4))) float f32x4_t;             // MFMA accumulator

__device__ inline unsigned short f2bf(float f) {              // f32 -> bf16 RNE
    unsigned int u = __float_as_uint(f);
    unsigned int r = (u + 0x7FFFu + ((u >> 16) & 1u)) >> 16;
    return (unsigned short)r;
}
__device__ inline float bf2f(unsigned short h) {
    return __uint_as_float((unsigned int)h << 16);
}

// --------------------------------------- prep: zero + seg + convert + out ----
__global__ void prep_kernel(const float* __restrict__ x, unsigned short* __restrict__ xb,
                            int* __restrict__ cursor, float* __restrict__ st,
                            const int* __restrict__ batch, int* __restrict__ seg,
                            float* __restrict__ out, const float* __restrict__ bf2,
                            int n, int G) {
    int i = blockIdx.x * blockDim.x + threadIdx.x;
    if (i < n * 8) {               // one ushort8 (8 feats) per thread; x row = 64 feats
        const float4* xf4 = (const float4*)x;
        float4 u = xf4[i * 2];
        float4 v = xf4[i * 2 + 1];
        ushort8_t h;
        h[0] = f2bf(u.x); h[1] = f2bf(u.y); h[2] = f2bf(u.z); h[3] = f2bf(u.w);
        h[4] = f2bf(v.x); h[5] = f2bf(v.y); h[6] = f2bf(v.z); h[7] = f2bf(v.w);
        ((ushort8_t*)xb)[i] = h;
    }
    if (i < n) cursor[i] = 0;
    if (i < 1028) st[i] = 0.f;     // st1[256] | st2[512] | stf[256] | ctr
    if (i < G) out[i] = bf2[0];
    if (i <= G) {
        if (i == G) { seg[G] = n; }
        else {
            int lo = 0, hi = n;
            while (lo < hi) {
                int mid = (lo + hi) >> 1;
                if (batch[mid] < i) lo = mid + 1; else hi = mid;
            }
            seg[i] = lo;
        }
    }
}

// ----------------------------------------------------------- bucket fill ----
__global__ void fillb_kernel(const int* __restrict__ ei, int* __restrict__ cursor,
                             unsigned int* __restrict__ recs, int E) {
    int e = blockIdx.x * blockDim.x + threadIdx.x;
    if (e >= E) return;
    int r = ei[e];
    int c = ei[E + e];
    int pos = atomicAdd(&cursor[c], 1);
    recs[(size_t)c * CAP + pos] = (unsigned int)r;
}

// ----------------------------------------- gather1 (inline w) + pack fused ----
// blocks [0, GB1): gather layer-1 (F=64, 2 slices, weight from cursor[r] inline)
// blocks [GB1, ..): stamp f16 weights into recs for gather2 (benign race: 4B
// stores are indivisible; gather readers mask r and never use the high bits).
__global__ __launch_bounds__(256)
void gather1_pack_kernel(const unsigned short* __restrict__ xb,
                         const int* __restrict__ cursor,
                         unsigned int* __restrict__ recs,
                         unsigned short* __restrict__ dst,
                         int n, int gps, int GB1) {
    const int bid = blockIdx.x;
    const int t   = threadIdx.x;

    if (bid >= GB1) {   // ---- pack region
        int i = (bid - GB1) * 256 + t;
        int node = i >> 6;
        if (node < n && (i & 63) < cursor[node]) {
            unsigned int r = recs[i] & 0xFFFFu;
            float w = rsqrtf((float)cursor[r] + 1.0f);
            recs[i] = (((unsigned int)__half_as_ushort(__float2half_rn(w))) << 16) | r;
        }
        return;
    }

    // ---- gather region: F=64, 8 lanes... W8=4 lanes/node, NPB=64 nodes/block
    int xl    = bid & 7;
    int slice = xl >> 2;
    int group = (bid >> 3) * 4 + (xl & 3);
    if (group >= gps) return;
    int local = t / 4;
    int lane  = t % 4;
    int node  = group * 64 + local;
    if (node >= n) return;
    int f8    = slice * 4 + lane;

    const ushort8_t* src8 = (const ushort8_t*)xb;
    int deg  = cursor[node];
    float di = rsqrtf((float)deg + 1.0f);
    ushort8_t sv = src8[(size_t)node * 8 + f8];
    float acc[8], acc2[8];
#pragma unroll
    for (int j = 0; j < 8; j++) { acc[j] = bf2f(sv[j]) * di; acc2[j] = 0.f; }

    int e  = node * CAP;
    int e1 = e + deg;
    for (; e + 1 < e1; e += 2) {
        int r0 = recs[e] & 0xFFFF;
        int r1 = recs[e + 1] & 0xFFFF;
        float w0 = rsqrtf((float)cursor[r0] + 1.0f);
        float w1 = rsqrtf((float)cursor[r1] + 1.0f);
        ushort8_t v0 = src8[(size_t)r0 * 8 + f8];
        ushort8_t v1 = src8[(size_t)r1 * 8 + f8];
#pragma unroll
        for (int j = 0; j < 8; j++) {
            acc[j]  = fmaf(bf2f(v0[j]), w0, acc[j]);
            acc2[j] = fmaf(bf2f(v1[j]), w1, acc2[j]);
        }
    }
    if (e < e1) {
        int r0 = recs[e] & 0xFFFF;
        float w0 = rsqrtf((float)cursor[r0] + 1.0f);
        ushort8_t v0 = src8[(size_t)r0 * 8 + f8];
#pragma unroll
        for (int j = 0; j < 8; j++) acc[j] = fmaf(bf2f(v0[j]), w0, acc[j]);
    }
    ushort8_t o;
#pragma unroll
    for (int j = 0; j < 8; j++) o[j] = f2bf((acc[j] + acc2[j]) * di);
    ((ushort8_t*)dst)[(size_t)node * 8 + f8] = o;
}

// ---------------------------------------------------- gather2 (packed recs) ----
// 4-edge unroll: 4 independent load chains for latency hiding.
template <int F, bool BN>
__launch_bounds__(256)
__global__ void gather_kernel(const unsigned short* __restrict__ src,
                              const int* __restrict__ cursor,
                              const unsigned int* __restrict__ recs,
                              const float* __restrict__ st, const float* __restrict__ gamma,
                              const float* __restrict__ beta, float inv_n,
                              unsigned short* __restrict__ dst, int n, int gps) {
    constexpr int F8  = F / 8;
    constexpr int W8  = F8 / 2;
    constexpr int NPB = 256 / W8;

    int bid = blockIdx.x;
    int xl  = bid & 7;
    int slice = xl >> 2;
    int group = (bid >> 3) * 4 + (xl & 3);
    if (group >= gps) return;

    int local = threadIdx.x / W8;
    int lane  = threadIdx.x % W8;
    int node  = group * NPB + local;
    if (node >= n) return;
    int f8    = slice * W8 + lane;
    int feat0 = f8 * 8;

    float sc[8], sh[8];
    if (BN) {
#pragma unroll
        for (int j = 0; j < 8; j++) {
            float m = st[feat0 + j] * inv_n;
            float v = st[F + feat0 + j] * inv_n - m * m;
            sc[j] = gamma[feat0 + j] * rsqrtf(v + EPS);
            sh[j] = beta[feat0 + j] - m * sc[j];
        }
    }

    const ushort8_t* src8 = (const ushort8_t*)src;
    int deg  = cursor[node];
    float di = rsqrtf((float)deg + 1.0f);
    ushort8_t sv = src8[(size_t)node * F8 + f8];
    float acc[8], acc2[8];
#pragma unroll
    for (int j = 0; j < 8; j++) {
        float f = bf2f(sv[j]);
        if (BN) f = fmaxf(fmaf(f, sc[j], sh[j]), 0.f);
        acc[j]  = f * di;
        acc2[j] = 0.f;
    }

    int e  = node * CAP;
    int e1 = e + deg;
    for (; e + 3 < e1; e += 4) {
        unsigned int q0 = recs[e],     q1 = recs[e + 1];
        unsigned int q2 = recs[e + 2], q3 = recs[e + 3];
        int r0 = q0 & 0xFFFF, r1 = q1 & 0xFFFF;
        int r2 = q2 & 0xFFFF, r3 = q3 & 0xFFFF;
        float w0 = __half2float(__ushort_as_half((unsigned short)(q0 >> 16)));
        float w1 = __half2float(__ushort_as_half((unsigned short)(q1 >> 16)));
        float w2 = __half2float(__ushort_as_half((unsigned short)(q2 >> 16)));
        float w3 = __half2float(__ushort_as_half((unsigned short)(q3 >> 16)));
        ushort8_t v0 = src8[(size_t)r0 * F8 + f8];
        ushort8_t v1 = src8[(size_t)r1 * F8 + f8];
        ushort8_t v2 = src8[(size_t)r2 * F8 + f8];
        ushort8_t v3 = src8[(size_t)r3 * F8 + f8];
#pragma unroll
        for (int j = 0; j < 8; j++) {
            float f0 = bf2f(v0[j]);
            float f1 = bf2f(v1[j]);
            float f2 = bf2f(v2[j]);
            float f3 = bf2f(v3[j]);
            if (BN) {
                f0 = fmaxf(fmaf(f0, sc[j], sh[j]), 0.f);
                f1 = fmaxf(fmaf(f1, sc[j], sh[j]), 0.f);
                f2 = fmaxf(fmaf(f2, sc[j], sh[j]), 0.f);
                f3 = fmaxf(fmaf(f3, sc[j], sh[j]), 0.f);
            }
            acc[j]  = fmaf(f0, w0, acc[j]);
            acc2[j] = fmaf(f1, w1, acc2[j]);
            acc[j]  = fmaf(f2, w2, acc[j]);
            acc2[j] = fmaf(f3, w3, acc2[j]);
        }
    }
    for (; e < e1; e++) {
        unsigned int q0 = recs[e];
        int r0 = q0 & 0xFFFF;
        float w0 = __half2float(__ushort_as_half((unsigned short)(q0 >> 16)));
        ushort8_t v0 = src8[(size_t)r0 * F8 + f8];
#pragma unroll
        for (int j = 0; j < 8; j++) {
            float f0 = bf2f(v0[j]);
            if (BN) f0 = fmaxf(fmaf(f0, sc[j], sh[j]), 0.f);
            acc[j] = fmaf(f0, w0, acc[j]);
        }
    }
    ushort8_t o;
#pragma unroll
    for (int j = 0; j < 8; j++) o[j] = f2bf((acc[j] + acc2[j]) * di);
    ((ushort8_t*)dst)[(size_t)node * F8 + f8] = o;
}

// --------------------------------------------------------- MFMA GEMM body ----
// OMODE: 0 f32, 1 bf16, 2 relu bf16. A_F32: stage-convert A from f32.
template <int K, int NTOT, int OMODE, bool A_F32, bool STATS>
__device__ void gemm_body(char* smemc, int row0, int col0,
                          const void* __restrict__ A, int lda,
                          const float* __restrict__ B, const float* __restrict__ bias,
                          void* __restrict__ Cout, int ldc, float* __restrict__ st, int M) {
    constexpr int KP = K + 8;
    unsigned short (*As)[KP] = (unsigned short (*)[KP])smemc;
    unsigned short (*Bs)[KP] = (unsigned short (*)[KP])(smemc + (size_t)64 * KP * 2);
    float (*sred)[64][2]     = (float (*)[64][2])(smemc + (size_t)2 * 64 * KP * 2);

    const int t    = threadIdx.x;
    const int lane = t & 63;
    const int wave = t >> 6;
    const int wr   = wave >> 1;
    const int wc   = wave & 1;

    constexpr int PA = (64 * K / 8) / 256;
#pragma unroll
    for (int p = 0; p < PA; p++) {
        int fi = t + 256 * p;
        int r  = fi / (K / 8);
        int c8 = fi % (K / 8);
        ushort8_t v = {};
        if (row0 + r < M) {
            if (A_F32) {
                const float* Af = (const float*)A;
                float4 u0 = *(const float4*)&Af[(size_t)(row0 + r) * lda + c8 * 8];
                float4 u1 = *(const float4*)&Af[(size_t)(row0 + r) * lda + c8 * 8 + 4];
                v[0] = f2bf(u0.x); v[1] = f2bf(u0.y); v[2] = f2bf(u0.z); v[3] = f2bf(u0.w);
                v[4] = f2bf(u1.x); v[5] = f2bf(u1.y); v[6] = f2bf(u1.z); v[7] = f2bf(u1.w);
            } else {
                v = *(const ushort8_t*)&((const unsigned short*)A)[(size_t)(row0 + r) * lda + c8 * 8];
            }
        }
        *(ushort8_t*)&As[r][c8 * 8] = v;
    }
    constexpr int PB = (K * 16) / 256;
#pragma unroll
    for (int p = 0; p < PB; p++) {
        int fi = t + 256 * p;
        int k  = fi >> 4;
        int c4 = fi & 15;
        float4 v = *(const float4*)&B[(size_t)k * NTOT + col0 + c4 * 4];
        Bs[c4 * 4 + 0][k] = f2bf(v.x);
        Bs[c4 * 4 + 1][k] = f2bf(v.y);
        Bs[c4 * 4 + 2][k] = f2bf(v.z);
        Bs[c4 * 4 + 3][k] = f2bf(v.w);
    }
    __syncthreads();

    const int l15 = lane & 15;
    const int l16 = lane >> 4;
    f32x4_t acc[2][2] = {};
#pragma unroll
    for (int ks = 0; ks < K / 32; ks++) {
        int koff = ks * 32 + l16 * 8;
        short8_t a0 = *(const short8_t*)&As[wr * 32 + l15][koff];
        short8_t a1 = *(const short8_t*)&As[wr * 32 + 16 + l15][koff];
        short8_t b0 = *(const short8_t*)&Bs[wc * 32 + l15][koff];
        short8_t b1 = *(const short8_t*)&Bs[wc * 32 + 16 + l15][koff];
        acc[0][0] = __builtin_amdgcn_mfma_f32_16x16x32_bf16(a0, b0, acc[0][0], 0, 0, 0);
        acc[0][1] = __builtin_amdgcn_mfma_f32_16x16x32_bf16(a0, b1, acc[0][1], 0, 0, 0);
        acc[1][0] = __builtin_amdgcn_mfma_f32_16x16x32_bf16(a1, b0, acc[1][0], 0, 0, 0);
        acc[1][1] = __builtin_amdgcn_mfma_f32_16x16x32_bf16(a1, b1, acc[1][1], 0, 0, 0);
    }

    float s1[2] = {0.f, 0.f}, s2[2] = {0.f, 0.f};
#pragma unroll
    for (int m = 0; m < 2; m++) {
#pragma unroll
        for (int j = 0; j < 4; j++) {
            int row = row0 + wr * 32 + m * 16 + l16 * 4 + j;
            if (row < M) {
#pragma unroll
                for (int nn = 0; nn < 2; nn++) {
                    int col = col0 + wc * 32 + nn * 16 + l15;
                    float v = acc[m][nn][j] + bias[col];
                    if (OMODE == 2) v = fmaxf(v, 0.f);
                    if (OMODE == 0) ((float*)Cout)[(size_t)row * ldc + col] = v;
                    else ((unsigned short*)Cout)[(size_t)row * ldc + col] = f2bf(v);
                    if (STATS) { s1[nn] += v; s2[nn] += v * v; }
                }
            }
        }
    }
    if (STATS) {
#pragma unroll
        for (int nn = 0; nn < 2; nn++) {
            s1[nn] += __shfl_xor(s1[nn], 16);
            s1[nn] += __shfl_xor(s1[nn], 32);
            s2[nn] += __shfl_xor(s2[nn], 16);
            s2[nn] += __shfl_xor(s2[nn], 32);
        }
        if (lane < 16) {
#pragma unroll
            for (int nn = 0; nn < 2; nn++) {
                sred[wr][wc * 32 + nn * 16 + lane][0] = s1[nn];
                sred[wr][wc * 32 + nn * 16 + lane][1] = s2[nn];
            }
        }
        __syncthreads();
        if (t < 64) {
            float a = sred[0][t][0] + sred[1][t][0];
            float b = sred[0][t][1] + sred[1][t][1];
            atomicAdd(&st[col0 + t], a);
            atomicAdd(&st[NTOT + col0 + t], b);
        }
    }
}

// --------------------------------------------------- gemm1 + solv FC fused ----
__global__ __launch_bounds__(256)
void gemm1_solv_kernel(const unsigned short* __restrict__ a1b,
                       const float* __restrict__ W1, const float* __restrict__ b1,
                       unsigned short* __restrict__ h1b, float* __restrict__ st1,
                       const float* __restrict__ sf, const float* __restrict__ Ws,
                       const float* __restrict__ bs, unsigned short* __restrict__ zs,
                       int n, int g1b, int G) {
    __shared__ alignas(16) char smem[35840];
    int bid = blockIdx.x;
    if (bid < g1b) {
        int MT = g1b / 2;
        gemm_body<64, 128, 1, false, true>(smem, (bid % MT) * 64, (bid / MT) * 64,
                                           a1b, 64, W1, b1, h1b, 128, st1, n);
    } else {
        int s = bid - g1b;
        gemm_body<128, 128, 2, true, false>(smem, (s >> 1) * 64, (s & 1) * 64,
                                            sf, 128, Ws, bs, zs, 128, nullptr, G);
    }
}

// gemm2: a2 = h1 @ W2 + b2 -> bf16 out (a2b), stats -> st2
__global__ __launch_bounds__(256)
void gemm2_kernel(const unsigned short* __restrict__ h1, const float* __restrict__ W2,
                  const float* __restrict__ b2, unsigned short* __restrict__ a2b,
                  float* __restrict__ st2, int n) {
    __shared__ alignas(16) char smem[35840];
    gemm_body<128, 256, 1, false, true>(smem, blockIdx.x * 64, blockIdx.y * 64,
                                        h1, 128, W2, b2, a2b, 256, st2, n);
}

// ------------------------------------------------------------------ pool ----
// block g: z[g][0..256) = bf16( mean_i relu(BN2(a2)) ); a2 is bf16.
__launch_bounds__(256)
__global__ void pool_kernel(const unsigned short* __restrict__ a2b, const int* __restrict__ seg,
                            const float* __restrict__ st2, const float* __restrict__ g2,
                            const float* __restrict__ be2, float inv_n,
                            unsigned short* __restrict__ z) {
    __shared__ float4 red[4][64];
    int g  = blockIdx.x;
    int t  = threadIdx.x;
    int r  = t >> 6;
    int f4 = t & 63;

    float4 sc, sh;
    {
        float m0 = st2[f4 * 4 + 0] * inv_n, m1 = st2[f4 * 4 + 1] * inv_n;
        float m2 = st2[f4 * 4 + 2] * inv_n, m3 = st2[f4 * 4 + 3] * inv_n;
        sc.x = g2[f4 * 4 + 0] * rsqrtf(st2[256 + f4 * 4 + 0] * inv_n - m0 * m0 + EPS);
        sc.y = g2[f4 * 4 + 1] * rsqrtf(st2[256 + f4 * 4 + 1] * inv_n - m1 * m1 + EPS);
        sc.z = g2[f4 * 4 + 2] * rsqrtf(st2[256 + f4 * 4 + 2] * inv_n - m2 * m2 + EPS);
        sc.w = g2[f4 * 4 + 3] * rsqrtf(st2[256 + f4 * 4 + 3] * inv_n - m3 * m3 + EPS);
        sh.x = be2[f4 * 4 + 0] - m0 * sc.x;
        sh.y = be2[f4 * 4 + 1] - m1 * sc.y;
        sh.z = be2[f4 * 4 + 2] - m2 * sc.z;
        sh.w = be2[f4 * 4 + 3] - m3 * sc.w;
    }

    int i0 = seg[g], i1 = seg[g + 1];
    float4 acc = make_float4(0.f, 0.f, 0.f, 0.f);
    for (int i = i0 + r; i < i1; i += 4) {
        ushort4 v = *(const ushort4*)&a2b[(size_t)i * 256 + f4 * 4];
        acc.x += fmaxf(fmaf(bf2f(v.x), sc.x, sh.x), 0.f);
        acc.y += fmaxf(fmaf(bf2f(v.y), sc.y, sh.y), 0.f);
        acc.z += fmaxf(fmaf(bf2f(v.z), sc.z, sh.z), 0.f);
        acc.w += fmaxf(fmaf(bf2f(v.w), sc.w, sh.w), 0.f);
    }
    red[r][f4] = acc;
    __syncthreads();
    if (t < 64) {
        float4 a = red[0][t], b = red[1][t], c = red[2][t], d = red[3][t];
        float inv = 1.0f / fmaxf((float)(i1 - i0), 1.f);
        ushort4 o;
        o.x = f2bf((a.x + b.x + c.x + d.x) * inv);
        o.y = f2bf((a.y + b.y + c.y + d.y) * inv);
        o.z = f2bf((a.z + b.z + c.z + d.z) * inv);
        o.w = f2bf((a.w + b.w + c.w + d.w) * inv);
        *(ushort4*)&z[(size_t)g * 256 + t * 4] = o;
    }
}

// ------------------------------------------------------------------ head ----
// 16 blocks. fc1 = [z(256) | zs(128)] @ Wf1 + bf1 -> stats -> spin barrier ->
// BN+ReLU+Wf2 on live accumulators -> atomicAdd into out (preset to bf2[0]).
__global__ __launch_bounds__(256)
void head_kernel(const unsigned short* __restrict__ z, const unsigned short* __restrict__ zs,
                 const float* __restrict__ Wf1, const float* __restrict__ bf1,
                 const float* __restrict__ gf, const float* __restrict__ bef,
                 const float* __restrict__ Wf2,
                 float* __restrict__ stf, int* __restrict__ ctr,
                 float* __restrict__ out, float inv_g, int nblocks) {
    constexpr int KP = 136;
    __shared__ unsigned short As[64][KP];
    __shared__ unsigned short Bs[64][KP];
    __shared__ float sred[2][64][2];

    const int t    = threadIdx.x;
    const int lane = t & 63;
    const int wave = t >> 6;
    const int wr   = wave >> 1;
    const int wc   = wave & 1;
    const int row0 = (blockIdx.x >> 1) * 64;
    const int col0 = (blockIdx.x & 1) * 64;
    const int l15  = lane & 15;
    const int l16  = lane >> 4;

    f32x4_t acc[2][2] = {};
    for (int kc = 0; kc < 3; kc++) {
        __syncthreads();
#pragma unroll
        for (int p = 0; p < 4; p++) {
            int fi = t + 256 * p;
            int r  = fi >> 4, c8 = fi & 15;
            const unsigned short* ap = (kc < 2)
                ? &z[(size_t)(row0 + r) * 256 + kc * 128 + c8 * 8]
                : &zs[(size_t)(row0 + r) * 128 + c8 * 8];
            *(ushort8_t*)&As[r][c8 * 8] = *(const ushort8_t*)ap;
        }
#pragma unroll
        for (int p = 0; p < 8; p++) {
            int fi = t + 256 * p;
            int k  = fi >> 4, c4 = fi & 15;
            float4 v = *(const float4*)&Wf1[(size_t)(kc * 128 + k) * 128 + col0 + c4 * 4];
            Bs[c4 * 4 + 0][k] = f2bf(v.x);
            Bs[c4 * 4 + 1][k] = f2bf(v.y);
            Bs[c4 * 4 + 2][k] = f2bf(v.z);
            Bs[c4 * 4 + 3][k] = f2bf(v.w);
        }
        __syncthreads();
#pragma unroll
        for (int ks = 0; ks < 4; ks++) {
            int koff = ks * 32 + l16 * 8;
            short8_t a0 = *(const short8_t*)&As[wr * 32 + l15][koff];
            short8_t a1 = *(const short8_t*)&As[wr * 32 + 16 + l15][koff];
            short8_t b0 = *(const short8_t*)&Bs[wc * 32 + l15][koff];
            short8_t b1 = *(const short8_t*)&Bs[wc * 32 + 16 + l15][koff];
            acc[0][0] = __builtin_amdgcn_mfma_f32_16x16x32_bf16(a0, b0, acc[0][0], 0, 0, 0);
            acc[0][1] = __builtin_amdgcn_mfma_f32_16x16x32_bf16(a0, b1, acc[0][1], 0, 0, 0);
            acc[1][0] = __builtin_amdgcn_mfma_f32_16x16x32_bf16(a1, b0, acc[1][0], 0, 0, 0);
            acc[1][1] = __builtin_amdgcn_mfma_f32_16x16x32_bf16(a1, b1, acc[1][1], 0, 0, 0);
        }
    }

    float s1[2] = {0.f, 0.f}, s2[2] = {0.f, 0.f};
#pragma unroll
    for (int m = 0; m < 2; m++)
#pragma unroll
        for (int j = 0; j < 4; j++)
#pragma unroll
            for (int nn = 0; nn < 2; nn++) {
                int col = col0 + wc * 32 + nn * 16 + l15;
                float v = acc[m][nn][j] + bf1[col];
                acc[m][nn][j] = v;
                s1[nn] += v;
                s2[nn] += v * v;
            }
#pragma unroll
    for (int nn = 0; nn < 2; nn++) {
        s1[nn] += __shfl_xor(s1[nn], 16);
        s1[nn] += __shfl_xor(s1[nn], 32);
        s2[nn] += __shfl_xor(s2[nn], 16);
        s2[nn] += __shfl_xor(s2[nn], 32);
    }
    if (lane < 16) {
#pragma unroll
        for (int nn = 0; nn < 2; nn++) {
            sred[wr][wc * 32 + nn * 16 + lane][0] = s1[nn];
            sred[wr][wc * 32 + nn * 16 + lane][1] = s2[nn];
        }
    }
    __syncthreads();
    if (t < 64) {
        atomicAdd(&stf[col0 + t],       sred[0][t][0] + sred[1][t][0]);
        atomicAdd(&stf[128 + col0 + t], sred[0][t][1] + sred[1][t][1]);
    }

    // device-scope spin barrier across the 16 head blocks
    __threadfence();
    __syncthreads();
    if (t == 0) {
        atomicAdd(ctr, 1);
        while (atomicAdd(ctr, 0) < nblocks) { }
    }
    __syncthreads();

    float* sflat = &sred[0][0][0];
    sflat[t] = atomicAdd(&stf[t], 0.f);   // coherent read of full stats
    __syncthreads();

#pragma unroll
    for (int m = 0; m < 2; m++)
#pragma unroll
        for (int j = 0; j < 4; j++) {
            float p = 0.f;
#pragma unroll
            for (int nn = 0; nn < 2; nn++) {
                int col = col0 + wc * 32 + nn * 16 + l15;
                float mean = sflat[col] * inv_g;
                float var  = sflat[128 + col] * inv_g - mean * mean;
                float sc   = gf[col] * rsqrtf(var + EPS);
                float sh   = bef[col] - mean * sc;
                p += fmaxf(fmaf(acc[m][nn][j], sc, sh), 0.f) * Wf2[col];
            }
            p += __shfl_xor(p, 1);
            p += __shfl_xor(p, 2);
            p += __shfl_xor(p, 4);
            p += __shfl_xor(p, 8);
            if (l15 == 0) {
                int row = wr * 32 + m * 16 + l16 * 4 + j;
                atomicAdd(&out[row0 + row], p);
            }
        }
}

// ---------------------------------------------------------------- launch ----
extern "C" void kernel_launch(void* const* d_in, const int* in_sizes, int n_in,
                              void* d_out, int out_size, void* d_ws, size_t ws_size,
                              hipStream_t stream) {
    const float* x    = (const float*)d_in[0];
    const int*   ei   = (const int*)d_in[1];
    const int*   batch= (const int*)d_in[2];
    const float* sf   = (const float*)d_in[3];
    const float* W1   = (const float*)d_in[4];
    const float* b1   = (const float*)d_in[5];
    const float* g1   = (const float*)d_in[6];
    const float* be1  = (const float*)d_in[7];
    const float* W2   = (const float*)d_in[8];
    const float* b2   = (const float*)d_in[9];
    const float* g2   = (const float*)d_in[10];
    const float* be2  = (const float*)d_in[11];
    const float* Ws   = (const float*)d_in[12];
    const float* bs   = (const float*)d_in[13];
    const float* Wf1  = (const float*)d_in[14];
    const float* bf1  = (const float*)d_in[15];
    const float* gf1  = (const float*)d_in[16];
    const float* bef1 = (const float*)d_in[17];
    const float* Wf2  = (const float*)d_in[18];
    const float* bf2  = (const float*)d_in[19];
    float* out = (float*)d_out;

    const int n = in_sizes[0] / 64;    // 20000 nodes
    const int E = in_sizes[1] / 2;     // 320000 edges
    const int G = in_sizes[3] / 128;   // 512 graphs

    // workspace (f32 units unless noted):
    // a2b[n*256 bf16 = 128n] | xb[32n] | a1b[64n] | h1b[64n] | z[G*128] |
    // zs[G*64] | st[1028] | cursor[n] | seg[G+1] | recs[n*CAP u32 = 64n]
    float* ws = (float*)d_ws;
    unsigned short* a2b = (unsigned short*)ws;
    unsigned short* xb  = (unsigned short*)(ws + (size_t)n * 128);
    unsigned short* a1b = (unsigned short*)(ws + (size_t)n * 160);
    unsigned short* h1b = (unsigned short*)(ws + (size_t)n * 224);
    unsigned short* z   = (unsigned short*)(ws + (size_t)n * 288);
    unsigned short* zs  = (unsigned short*)(ws + (size_t)n * 288 + (size_t)G * 128);
    float* st   = ws + (size_t)n * 288 + (size_t)G * 192;
    float* st1  = st;
    float* st2  = st + 256;
    float* stf  = st + 768;
    int*   ctr  = (int*)(st + 1024);
    int*   cursor = (int*)(st + 1028);
    int*   seg    = cursor + n;
    unsigned int* recs = (unsigned int*)(seg + G + 1);

    const float inv_nn = 1.0f / (float)n;
    const float inv_gg = 1.0f / (float)G;
    const int MT = (n + 63) / 64;

    prep_kernel<<<(n * 8 + 255) / 256, 256, 0, stream>>>(x, xb, cursor, st, batch, seg,
                                                         out, bf2, n, G);
    fillb_kernel<<<(E + 255) / 256, 256, 0, stream>>>(ei, cursor, recs, E);

    // gather1 (inline-w) + pack fused
    {
        int gps = (n + 63) / 64;
        int GB1 = ((gps + 3) / 4) * 8;
        int PB  = (n * CAP + 255) / 256;
        gather1_pack_kernel<<<GB1 + PB, 256, 0, stream>>>(xb, cursor, recs, a1b, n, gps, GB1);
    }

    // gemm1 (a1 = xa@W1+b1, bf16 -> h1b, stats->st1)  +  solv FC -> zs
    gemm1_solv_kernel<<<MT * 2 + (G / 64) * 2, 256, 0, stream>>>(
        a1b, W1, b1, h1b, st1, sf, Ws, bs, zs, n, MT * 2, G);

    // gather2: h1 = A_hat @ relu(BN1(a1))  (packed recs; -> a1b)
    {
        int gps = (n + 31) / 32;
        int grid = ((gps + 3) / 4) * 8;
        gather_kernel<128, true><<<grid, 256, 0, stream>>>(
            h1b, cursor, recs, st1, g1, be1, inv_nn, a1b, n, gps);
    }

    // gemm2: a2 = h1 @ W2 + b2 (bf16 out), stats -> st2
    gemm2_kernel<<<dim3(MT, 4), 256, 0, stream>>>(a1b, W2, b2, a2b, st2, n);

    // pool -> z (bf16 [G][256])
    pool_kernel<<<G, 256, 0, stream>>>(a2b, seg, st2, g2, be2, inv_nn, z);

    // head: fc1 + stats + barrier + final
    head_kernel<<<(G / 64) * 2, 256, 0, stream>>>(z, zs, Wf1, bf1, gf1, bef1, Wf2,
                                                  stf, ctr, out, inv_gg, (G / 64) * 2);
}